// Round 1
// baseline (228.589 us; speedup 1.0000x reference)
//
#include <hip/hip_runtime.h>

typedef __attribute__((ext_vector_type(8))) short bf16x8;
typedef __attribute__((ext_vector_type(4))) float f32x4;

#define MFMA16(a, b, c) __builtin_amdgcn_mfma_f32_16x16x32_bf16(a, b, c, 0, 0, 0)
#define LOG2E 1.4426950408889634f

// Problem constants
#define BB 2
#define TT 2048
#define CC 768
#define HH 12
#define DD 64
#define MM (BB * TT)      // 4096
#define N1 (3 * CC)       // 2304

static __device__ __forceinline__ unsigned short f2bf(float f) {
  union { float f; unsigned u; } v; v.f = f;
  unsigned r = (v.u + 0x7FFFu + ((v.u >> 16) & 1u)) >> 16;
  return (unsigned short)r;
}

// ---------- convert fp32 -> bf16 (4 elems/thread) ----------
__global__ __launch_bounds__(256) void k_cvt(const float* __restrict__ x,
                                             unsigned short* __restrict__ o) {
  int i = blockIdx.x * 256 + threadIdx.x;
  float4 v = reinterpret_cast<const float4*>(x)[i];
  ushort4 r;
  r.x = f2bf(v.x); r.y = f2bf(v.y); r.z = f2bf(v.z); r.w = f2bf(v.w);
  reinterpret_cast<ushort4*>(o)[i] = r;
}

// ---------- transpose + convert: W [K][N] f32 -> Wt [N][K] bf16 ----------
__global__ __launch_bounds__(256) void k_tr(const float* __restrict__ W,
                                            unsigned short* __restrict__ Wt,
                                            int K, int N) {
  __shared__ float tile[32][33];
  int tx = threadIdx.x, ty = threadIdx.y;
  int n0 = blockIdx.x * 32, k0 = blockIdx.y * 32;
#pragma unroll
  for (int i = 0; i < 4; ++i)
    tile[ty + i * 8][tx] = W[(size_t)(k0 + ty + i * 8) * N + n0 + tx];
  __syncthreads();
#pragma unroll
  for (int i = 0; i < 4; ++i)
    Wt[(size_t)(n0 + ty + i * 8) * K + k0 + tx] = f2bf(tile[tx][ty + i * 8]);
}

// ---------- bf16 GEMM, C[m][n] = sum_k A[m][k]*Bt[n][k] + bias[n] ----------
// MODE 0: write fp32 Cout[m][n].
// MODE 1: scatter QKV: n<768 -> Q (scaled 0.125) [bh][T][D]; n<1536 -> K [bh][T][D];
//         else -> V transposed [bh][D][T].
template <int MODE>
__global__ __launch_bounds__(256) void k_gemm(
    const unsigned short* __restrict__ A, const unsigned short* __restrict__ Bt,
    const float* __restrict__ bias, float* __restrict__ Cout, int N, int K,
    unsigned short* __restrict__ Qb, unsigned short* __restrict__ Kb,
    unsigned short* __restrict__ Vt) {
  __shared__ __align__(16) unsigned short As[128 * 32];
  __shared__ __align__(16) unsigned short Bs[128 * 32];
  const int tid = threadIdx.x;
  const int lane = tid & 63;
  const int wid = tid >> 6;
  const int l15 = lane & 15, l4 = lane >> 4;
  const int wr = wid >> 1, wc = wid & 1;
  const int brow = blockIdx.x * 128, bcol = blockIdx.y * 128;

  f32x4 acc[4][4] = {};

  const int u0 = tid, u1 = tid + 256;
  const int row0 = u0 >> 2, c0 = (u0 & 3) * 8;
  const int row1 = u1 >> 2, c1 = (u1 & 3) * 8;

  // prefetch k-step 0 into regs
  uint4 pa0 = *reinterpret_cast<const uint4*>(A + (size_t)(brow + row0) * K + c0);
  uint4 pa1 = *reinterpret_cast<const uint4*>(A + (size_t)(brow + row1) * K + c1);
  uint4 pb0 = *reinterpret_cast<const uint4*>(Bt + (size_t)(bcol + row0) * K + c0);
  uint4 pb1 = *reinterpret_cast<const uint4*>(Bt + (size_t)(bcol + row1) * K + c1);

  const int NK = K / 32;
  for (int ks = 0; ks < NK; ++ks) {
    __syncthreads();
    reinterpret_cast<uint4*>(As)[u0] = pa0;
    reinterpret_cast<uint4*>(As)[u1] = pa1;
    reinterpret_cast<uint4*>(Bs)[u0] = pb0;
    reinterpret_cast<uint4*>(Bs)[u1] = pb1;
    __syncthreads();
    if (ks + 1 < NK) {
      const int k0 = (ks + 1) * 32;
      pa0 = *reinterpret_cast<const uint4*>(A + (size_t)(brow + row0) * K + k0 + c0);
      pa1 = *reinterpret_cast<const uint4*>(A + (size_t)(brow + row1) * K + k0 + c1);
      pb0 = *reinterpret_cast<const uint4*>(Bt + (size_t)(bcol + row0) * K + k0 + c0);
      pb1 = *reinterpret_cast<const uint4*>(Bt + (size_t)(bcol + row1) * K + k0 + c1);
    }
    bf16x8 af[4], bfr[4];
#pragma unroll
    for (int mi = 0; mi < 4; ++mi)
      af[mi] = *reinterpret_cast<const bf16x8*>(&As[(wr * 64 + mi * 16 + l15) * 32 + l4 * 8]);
#pragma unroll
    for (int ni = 0; ni < 4; ++ni)
      bfr[ni] = *reinterpret_cast<const bf16x8*>(&Bs[(wc * 64 + ni * 16 + l15) * 32 + l4 * 8]);
#pragma unroll
    for (int mi = 0; mi < 4; ++mi)
#pragma unroll
      for (int ni = 0; ni < 4; ++ni)
        acc[mi][ni] = MFMA16(af[mi], bfr[ni], acc[mi][ni]);
  }

  // epilogue
#pragma unroll
  for (int mi = 0; mi < 4; ++mi) {
    const int m0 = brow + wr * 64 + mi * 16 + l4 * 4;
#pragma unroll
    for (int ni = 0; ni < 4; ++ni) {
      const int n = bcol + wc * 64 + ni * 16 + l15;
      const float bv = bias[n];
      if (MODE == 0) {
#pragma unroll
        for (int r = 0; r < 4; ++r)
          Cout[(size_t)(m0 + r) * N + n] = acc[mi][ni][r] + bv;
      } else {
        const int sec = n / CC;
        const int nn = n - sec * CC;
        const int h = nn >> 6, d = nn & 63;
        const int b = m0 >> 11;        // T = 2048
        const int t0 = m0 & 2047;
        const int base = (b * HH + h) * TT;
        if (sec == 0) {
#pragma unroll
          for (int r = 0; r < 4; ++r)
            Qb[(size_t)(base + t0 + r) * DD + d] = f2bf((acc[mi][ni][r] + bv) * 0.125f);
        } else if (sec == 1) {
#pragma unroll
          for (int r = 0; r < 4; ++r)
            Kb[(size_t)(base + t0 + r) * DD + d] = f2bf(acc[mi][ni][r] + bv);
        } else {
          ushort4 pk;
          pk.x = f2bf(acc[mi][ni][0] + bv);
          pk.y = f2bf(acc[mi][ni][1] + bv);
          pk.z = f2bf(acc[mi][ni][2] + bv);
          pk.w = f2bf(acc[mi][ni][3] + bv);
          *reinterpret_cast<ushort4*>(&Vt[(size_t)((b * HH + h) * DD + d) * TT + t0]) = pk;
        }
      }
    }
  }
}

// ---------- causal flash attention ----------
// grid: (T/64, B*H); 4 waves, wave w owns 16 q-rows. K/V straight from global (L2).
__global__ __launch_bounds__(256) void k_attn(
    const unsigned short* __restrict__ Q, const unsigned short* __restrict__ Kb,
    const unsigned short* __restrict__ Vt, const int* __restrict__ mask,
    unsigned short* __restrict__ AO) {
  __shared__ __align__(16) unsigned short sP[4][16][72];
  const int tid = threadIdx.x;
  const int lane = tid & 63;
  const int wid = tid >> 6;
  const int l15 = lane & 15, l4 = lane >> 4;
  const int qb = blockIdx.x, bh = blockIdx.y;
  const int b = bh / HH, h = bh - b * HH;
  const unsigned short* Qh = Q + (size_t)bh * TT * DD;
  const unsigned short* Kh = Kb + (size_t)bh * TT * DD;
  const unsigned short* Vh = Vt + (size_t)bh * DD * TT;
  const int q0 = qb * 64 + wid * 16;

  const bf16x8 aq0 = *reinterpret_cast<const bf16x8*>(&Qh[(q0 + l15) * DD + l4 * 8]);
  const bf16x8 aq1 = *reinterpret_cast<const bf16x8*>(&Qh[(q0 + l15) * DD + 32 + l4 * 8]);

  f32x4 o[4] = {};
  float mrow[4] = {-1e30f, -1e30f, -1e30f, -1e30f};
  float lrow[4] = {0.f, 0.f, 0.f, 0.f};

  const int nt = qb + 1;
  for (int tk = 0; tk < nt; ++tk) {
    const int kv0 = tk * 64;
    f32x4 s[4];
#pragma unroll
    for (int ni = 0; ni < 4; ++ni) {
      const unsigned short* kp = &Kh[(kv0 + ni * 16 + l15) * DD + l4 * 8];
      bf16x8 bk0 = *reinterpret_cast<const bf16x8*>(kp);
      bf16x8 bk1 = *reinterpret_cast<const bf16x8*>(kp + 32);
      f32x4 z = {0.f, 0.f, 0.f, 0.f};
      z = MFMA16(aq0, bk0, z);
      z = MFMA16(aq1, bk1, z);
      s[ni] = z;
    }
    // attention_mask (key-wise) + causal mask
#pragma unroll
    for (int ni = 0; ni < 4; ++ni) {
      const int ki = kv0 + ni * 16 + l15;
      if (mask[b * TT + ki] == 0) {
#pragma unroll
        for (int r = 0; r < 4; ++r) s[ni][r] = -1e30f;
      }
    }
    if (kv0 + 63 > q0) {
#pragma unroll
      for (int ni = 0; ni < 4; ++ni) {
        const int ki = kv0 + ni * 16 + l15;
#pragma unroll
        for (int r = 0; r < 4; ++r)
          if (ki > q0 + l4 * 4 + r) s[ni][r] = -1e30f;
      }
    }
    // online softmax (row r' = l4*4+r; reduce across the 16 col-lanes)
    float al[4];
#pragma unroll
    for (int r = 0; r < 4; ++r) {
      float mx = fmaxf(fmaxf(s[0][r], s[1][r]), fmaxf(s[2][r], s[3][r]));
      mx = fmaxf(mx, __shfl_xor(mx, 1));
      mx = fmaxf(mx, __shfl_xor(mx, 2));
      mx = fmaxf(mx, __shfl_xor(mx, 4));
      mx = fmaxf(mx, __shfl_xor(mx, 8));
      const float mn = fmaxf(mrow[r], mx);
      al[r] = __builtin_amdgcn_exp2f((mrow[r] - mn) * LOG2E);
      mrow[r] = mn;
    }
#pragma unroll
    for (int ni = 0; ni < 4; ++ni)
#pragma unroll
      for (int r = 0; r < 4; ++r) {
        const float sv = s[ni][r];
        s[ni][r] = (sv <= -1e29f) ? 0.f : __builtin_amdgcn_exp2f((sv - mrow[r]) * LOG2E);
      }
#pragma unroll
    for (int r = 0; r < 4; ++r) {
      float ps = s[0][r] + s[1][r] + s[2][r] + s[3][r];
      ps += __shfl_xor(ps, 1);
      ps += __shfl_xor(ps, 2);
      ps += __shfl_xor(ps, 4);
      ps += __shfl_xor(ps, 8);
      lrow[r] = lrow[r] * al[r] + ps;
    }
#pragma unroll
    for (int di = 0; di < 4; ++di)
#pragma unroll
      for (int r = 0; r < 4; ++r) o[di][r] *= al[r];
    // P: D-layout -> LDS -> A-fragment layout
#pragma unroll
    for (int ni = 0; ni < 4; ++ni)
#pragma unroll
      for (int r = 0; r < 4; ++r)
        sP[wid][l4 * 4 + r][ni * 16 + l15] = f2bf(s[ni][r]);
    __syncthreads();
    const bf16x8 p0 = *reinterpret_cast<const bf16x8*>(&sP[wid][l15][l4 * 8]);
    const bf16x8 p1 = *reinterpret_cast<const bf16x8*>(&sP[wid][l15][32 + l4 * 8]);
#pragma unroll
    for (int di = 0; di < 4; ++di) {
      const unsigned short* vp = &Vh[(di * 16 + l15) * TT + kv0 + l4 * 8];
      bf16x8 v0 = *reinterpret_cast<const bf16x8*>(vp);
      bf16x8 v1 = *reinterpret_cast<const bf16x8*>(vp + 32);
      o[di] = MFMA16(p0, v0, o[di]);
      o[di] = MFMA16(p1, v1, o[di]);
    }
  }
  float rl[4];
#pragma unroll
  for (int r = 0; r < 4; ++r) rl[r] = 1.f / lrow[r];
#pragma unroll
  for (int di = 0; di < 4; ++di) {
    const int d = h * DD + di * 16 + l15;
#pragma unroll
    for (int r = 0; r < 4; ++r) {
      const int t = q0 + l4 * 4 + r;
      AO[(size_t)(b * TT + t) * CC + d] = f2bf(o[di][r] * rl[r]);
    }
  }
}

extern "C" void kernel_launch(void* const* d_in, const int* in_sizes, int n_in,
                              void* d_out, int out_size, void* d_ws, size_t ws_size,
                              hipStream_t stream) {
  const float* x   = (const float*)d_in[0];
  const int* mask  = (const int*)d_in[1];
  const float* Wa  = (const float*)d_in[2];
  const float* ba  = (const float*)d_in[3];
  const float* Wp  = (const float*)d_in[4];
  const float* bp  = (const float*)d_in[5];
  float* out = (float*)d_out;

  char* ws = (char*)d_ws;
  unsigned short* Xb  = (unsigned short*)(ws);                 // [4096][768]
  unsigned short* WaT = (unsigned short*)(ws + 6291456);       // [2304][768]
  unsigned short* WpT = (unsigned short*)(ws + 9830400);       // [768][768]
  unsigned short* Qb  = (unsigned short*)(ws + 11010048);      // [24][2048][64]
  unsigned short* Kb  = (unsigned short*)(ws + 17301504);      // [24][2048][64]
  unsigned short* Vt  = (unsigned short*)(ws + 23592960);      // [24][64][2048]
  unsigned short* AO  = (unsigned short*)(ws + 29884416);      // [4096][768]

  k_cvt<<<dim3((MM * CC) / 4 / 256), dim3(256), 0, stream>>>(x, Xb);
  k_tr<<<dim3(N1 / 32, CC / 32), dim3(32, 8), 0, stream>>>(Wa, WaT, CC, N1);
  k_tr<<<dim3(CC / 32, CC / 32), dim3(32, 8), 0, stream>>>(Wp, WpT, CC, CC);

  k_gemm<1><<<dim3(MM / 128, N1 / 128), dim3(256), 0, stream>>>(
      Xb, WaT, ba, nullptr, N1, CC, Qb, Kb, Vt);

  k_attn<<<dim3(TT / 64, BB * HH), dim3(256), 0, stream>>>(Qb, Kb, Vt, mask, AO);

  k_gemm<0><<<dim3(MM / 128, CC / 128), dim3(256), 0, stream>>>(
      AO, WpT, bp, out, CC, CC, nullptr, nullptr, nullptr);
}

// Round 2
// 131.457 us; speedup vs baseline: 1.7389x; 1.7389x over previous
//
#include <hip/hip_runtime.h>

typedef __attribute__((ext_vector_type(8))) short bf16x8;
typedef __attribute__((ext_vector_type(4))) float f32x4;
typedef __attribute__((ext_vector_type(16))) float f32x16;

#define MFMA16(a, b, c) __builtin_amdgcn_mfma_f32_16x16x32_bf16(a, b, c, 0, 0, 0)
#define MFMA32(a, b, c) __builtin_amdgcn_mfma_f32_32x32x16_bf16(a, b, c, 0, 0, 0)
#define LOG2E 1.4426950408889634f

// Problem constants
#define BB 2
#define TT 2048
#define CC 768
#define HH 12
#define DD 64
#define MM (BB * TT)      // 4096
#define N1 (3 * CC)       // 2304

static __device__ __forceinline__ unsigned short f2bf(float f) {
  union { float f; unsigned u; } v; v.f = f;
  unsigned r = (v.u + 0x7FFFu + ((v.u >> 16) & 1u)) >> 16;
  return (unsigned short)r;
}

// ---------- convert fp32 -> bf16 (4 elems/thread) ----------
__global__ __launch_bounds__(256) void k_cvt(const float* __restrict__ x,
                                             unsigned short* __restrict__ o) {
  int i = blockIdx.x * 256 + threadIdx.x;
  float4 v = reinterpret_cast<const float4*>(x)[i];
  ushort4 r;
  r.x = f2bf(v.x); r.y = f2bf(v.y); r.z = f2bf(v.z); r.w = f2bf(v.w);
  reinterpret_cast<ushort4*>(o)[i] = r;
}

// ---------- mask -> bitmask: mbits[b*64 + dw] bit j = mask[b*2048 + dw*32 + j] ----------
__global__ __launch_bounds__(128) void k_mbits(const int* __restrict__ mask,
                                               unsigned int* __restrict__ mb) {
  int i = threadIdx.x;  // 0..127
  unsigned bits = 0;
  const int* p = mask + i * 32;
#pragma unroll
  for (int j = 0; j < 32; ++j) bits |= (p[j] != 0 ? 1u : 0u) << j;
  mb[i] = bits;
}

// ---------- transpose + convert: W [K][N] f32 -> Wt [N][K] bf16 ----------
__global__ __launch_bounds__(256) void k_tr(const float* __restrict__ W,
                                            unsigned short* __restrict__ Wt,
                                            int K, int N) {
  __shared__ float tile[32][33];
  int tx = threadIdx.x, ty = threadIdx.y;
  int n0 = blockIdx.x * 32, k0 = blockIdx.y * 32;
#pragma unroll
  for (int i = 0; i < 4; ++i)
    tile[ty + i * 8][tx] = W[(size_t)(k0 + ty + i * 8) * N + n0 + tx];
  __syncthreads();
#pragma unroll
  for (int i = 0; i < 4; ++i)
    Wt[(size_t)(n0 + ty + i * 8) * K + k0 + tx] = f2bf(tile[tx][ty + i * 8]);
}

// ---------- bf16 GEMM, C[m][n] = sum_k A[m][k]*Bt[n][k] + bias[n] ----------
template <int MODE>
__global__ __launch_bounds__(256) void k_gemm(
    const unsigned short* __restrict__ A, const unsigned short* __restrict__ Bt,
    const float* __restrict__ bias, float* __restrict__ Cout, int N, int K,
    unsigned short* __restrict__ Qb, unsigned short* __restrict__ Kb,
    unsigned short* __restrict__ Vt) {
  __shared__ __align__(16) unsigned short As[128 * 32];
  __shared__ __align__(16) unsigned short Bs[128 * 32];
  const int tid = threadIdx.x;
  const int lane = tid & 63;
  const int wid = tid >> 6;
  const int l15 = lane & 15, l4 = lane >> 4;
  const int wr = wid >> 1, wc = wid & 1;
  const int brow = blockIdx.x * 128, bcol = blockIdx.y * 128;

  f32x4 acc[4][4] = {};

  const int u0 = tid, u1 = tid + 256;
  const int row0 = u0 >> 2, c0 = (u0 & 3) * 8;
  const int row1 = u1 >> 2, c1 = (u1 & 3) * 8;

  uint4 pa0 = *reinterpret_cast<const uint4*>(A + (size_t)(brow + row0) * K + c0);
  uint4 pa1 = *reinterpret_cast<const uint4*>(A + (size_t)(brow + row1) * K + c1);
  uint4 pb0 = *reinterpret_cast<const uint4*>(Bt + (size_t)(bcol + row0) * K + c0);
  uint4 pb1 = *reinterpret_cast<const uint4*>(Bt + (size_t)(bcol + row1) * K + c1);

  const int NK = K / 32;
  for (int ks = 0; ks < NK; ++ks) {
    __syncthreads();
    reinterpret_cast<uint4*>(As)[u0] = pa0;
    reinterpret_cast<uint4*>(As)[u1] = pa1;
    reinterpret_cast<uint4*>(Bs)[u0] = pb0;
    reinterpret_cast<uint4*>(Bs)[u1] = pb1;
    __syncthreads();
    if (ks + 1 < NK) {
      const int k0 = (ks + 1) * 32;
      pa0 = *reinterpret_cast<const uint4*>(A + (size_t)(brow + row0) * K + k0 + c0);
      pa1 = *reinterpret_cast<const uint4*>(A + (size_t)(brow + row1) * K + k0 + c1);
      pb0 = *reinterpret_cast<const uint4*>(Bt + (size_t)(bcol + row0) * K + k0 + c0);
      pb1 = *reinterpret_cast<const uint4*>(Bt + (size_t)(bcol + row1) * K + k0 + c1);
    }
    bf16x8 af[4], bfr[4];
#pragma unroll
    for (int mi = 0; mi < 4; ++mi)
      af[mi] = *reinterpret_cast<const bf16x8*>(&As[(wr * 64 + mi * 16 + l15) * 32 + l4 * 8]);
#pragma unroll
    for (int ni = 0; ni < 4; ++ni)
      bfr[ni] = *reinterpret_cast<const bf16x8*>(&Bs[(wc * 64 + ni * 16 + l15) * 32 + l4 * 8]);
#pragma unroll
    for (int mi = 0; mi < 4; ++mi)
#pragma unroll
      for (int ni = 0; ni < 4; ++ni)
        acc[mi][ni] = MFMA16(af[mi], bfr[ni], acc[mi][ni]);
  }

#pragma unroll
  for (int mi = 0; mi < 4; ++mi) {
    const int m0 = brow + wr * 64 + mi * 16 + l4 * 4;
#pragma unroll
    for (int ni = 0; ni < 4; ++ni) {
      const int n = bcol + wc * 64 + ni * 16 + l15;
      const float bv = bias[n];
      if (MODE == 0) {
#pragma unroll
        for (int r = 0; r < 4; ++r)
          Cout[(size_t)(m0 + r) * N + n] = acc[mi][ni][r] + bv;
      } else {
        const int sec = n / CC;
        const int nn = n - sec * CC;
        const int h = nn >> 6, d = nn & 63;
        const int b = m0 >> 11;
        const int t0 = m0 & 2047;
        const int base = (b * HH + h) * TT;
        if (sec == 0) {
#pragma unroll
          for (int r = 0; r < 4; ++r)
            Qb[(size_t)(base + t0 + r) * DD + d] = f2bf((acc[mi][ni][r] + bv) * 0.125f);
        } else if (sec == 1) {
#pragma unroll
          for (int r = 0; r < 4; ++r)
            Kb[(size_t)(base + t0 + r) * DD + d] = f2bf(acc[mi][ni][r] + bv);
        } else {
          ushort4 pk;
          pk.x = f2bf(acc[mi][ni][0] + bv);
          pk.y = f2bf(acc[mi][ni][1] + bv);
          pk.z = f2bf(acc[mi][ni][2] + bv);
          pk.w = f2bf(acc[mi][ni][3] + bv);
          *reinterpret_cast<ushort4*>(&Vt[(size_t)((b * HH + h) * DD + d) * TT + t0]) = pk;
        }
      }
    }
  }
}

// ---------- causal flash attention, 1 wave per 32 q-rows, 32x32 swapped QK^T ----------
__device__ __forceinline__ void loadk(bf16x8 (&dst)[2][4], const unsigned short* Kh,
                                      int kv0, int l31, int h8) {
#pragma unroll
  for (int kg = 0; kg < 2; ++kg)
#pragma unroll
    for (int dg = 0; dg < 4; ++dg)
      dst[kg][dg] = *reinterpret_cast<const bf16x8*>(
          &Kh[(size_t)(kv0 + kg * 32 + l31) * DD + dg * 16 + h8]);
}

__device__ __forceinline__ void attn_tile(
    int kv0, const bf16x8 (&kf)[2][4], uint2 mb, const bf16x8 (&qf)[4],
    const unsigned short* __restrict__ Vh, int q0, int l31, int h, int h8,
    f32x16& o0, f32x16& o1, float& mrow, float& lrow) {
  // V early issue (consumed after softmax; latency hidden)
  bf16x8 vf0[4], vf1[4];
#pragma unroll
  for (int kc = 0; kc < 4; ++kc) {
    vf0[kc] = *reinterpret_cast<const bf16x8*>(&Vh[(size_t)l31 * TT + kv0 + kc * 16 + h8]);
    vf1[kc] = *reinterpret_cast<const bf16x8*>(&Vh[(size_t)(32 + l31) * TT + kv0 + kc * 16 + h8]);
  }

  // QK^T swapped: S^T[key][q]; lane holds q = l31, key = kg*32 + (r&3)+8*(r>>2)+4h
  f32x16 s0 = {}, s1 = {};
#pragma unroll
  for (int dg = 0; dg < 4; ++dg) s0 = MFMA32(kf[0][dg], qf[dg], s0);
#pragma unroll
  for (int dg = 0; dg < 4; ++dg) s1 = MFMA32(kf[1][dg], qf[dg], s1);

  // attention_mask (key-wise) via bitmask; skip when all ones
  if ((mb.x & mb.y) != 0xffffffffu) {
#pragma unroll
    for (int r = 0; r < 16; ++r) {
      const int ki = (r & 3) + 8 * (r >> 2) + 4 * h;
      if (!((mb.x >> ki) & 1u)) s0[r] = -1e30f;
      if (!((mb.y >> ki) & 1u)) s1[r] = -1e30f;
    }
  }
  // causal
  if (kv0 + 63 > q0) {
    const int q = q0 + l31;
#pragma unroll
    for (int r = 0; r < 16; ++r) {
      const int ki = kv0 + (r & 3) + 8 * (r >> 2) + 4 * h;
      if (ki > q) s0[r] = -1e30f;
      if (ki + 32 > q) s1[r] = -1e30f;
    }
  }

  // online softmax per q (in-lane over 32 + one xor-32 shuffle)
  float pmax = s0[0];
#pragma unroll
  for (int r = 1; r < 16; ++r) pmax = fmaxf(pmax, s0[r]);
#pragma unroll
  for (int r = 0; r < 16; ++r) pmax = fmaxf(pmax, s1[r]);
  pmax = fmaxf(pmax, __shfl_xor(pmax, 32));

  if (!__all(pmax - mrow <= 8.0f)) {        // defer-max (T13)
    const float mnew = fmaxf(mrow, pmax);
    const float al = __builtin_amdgcn_exp2f((mrow - mnew) * LOG2E);
    lrow *= al;
    mrow = mnew;
#pragma unroll
    for (int r = 0; r < 16; ++r) {
      const float ab = __shfl(al, (r & 3) + 8 * (r >> 2) + 4 * h);
      o0[r] *= ab;
      o1[r] *= ab;
    }
  }

  float ps = 0.f;
#pragma unroll
  for (int r = 0; r < 16; ++r) {
    s0[r] = __builtin_amdgcn_exp2f((s0[r] - mrow) * LOG2E);
    ps += s0[r];
  }
#pragma unroll
  for (int r = 0; r < 16; ++r) {
    s1[r] = __builtin_amdgcn_exp2f((s1[r] - mrow) * LOG2E);
    ps += s1[r];
  }
  ps += __shfl_xor(ps, 32);
  lrow += ps;

  // pack P to bf16 pairs: pk[kg][m][j] = keys (kg*32 + 4m + 4h + 2j, +1)
  unsigned pk0[4][2], pk1[4][2];
#pragma unroll
  for (int m = 0; m < 4; ++m)
#pragma unroll
    for (int j = 0; j < 2; ++j) {
      pk0[m][j] = (unsigned)f2bf(s0[4 * m + 2 * j]) |
                  ((unsigned)f2bf(s0[4 * m + 2 * j + 1]) << 16);
      pk1[m][j] = (unsigned)f2bf(s1[4 * m + 2 * j]) |
                  ((unsigned)f2bf(s1[4 * m + 2 * j + 1]) << 16);
    }

  // PV: per 16-key slot kc, build A-frag P[q=l31][key=kc*16+8h+j] via one xor-32 exchange
#pragma unroll
  for (int kc = 0; kc < 4; ++kc) {
    const unsigned (&pkk)[4][2] = (kc < 2) ? pk0 : pk1;
    const int c1 = (kc & 1) * 2;
    const unsigned v0 = h ? pkk[c1][0] : pkk[c1 + 1][0];  // publish the partner's variant
    const unsigned v1 = h ? pkk[c1][1] : pkk[c1 + 1][1];
    const unsigned r0 = (unsigned)__shfl_xor((int)v0, 32);
    const unsigned r1 = (unsigned)__shfl_xor((int)v1, 32);
    union { unsigned u[4]; bf16x8 v; } af;
    af.u[0] = h ? r0 : pkk[c1][0];
    af.u[1] = h ? r1 : pkk[c1][1];
    af.u[2] = h ? pkk[c1 + 1][0] : r0;
    af.u[3] = h ? pkk[c1 + 1][1] : r1;
    o0 = MFMA32(af.v, vf0[kc], o0);
    o1 = MFMA32(af.v, vf1[kc], o1);
  }
}

__global__ __launch_bounds__(64, 2) void k_attn(
    const unsigned short* __restrict__ Q, const unsigned short* __restrict__ Kb,
    const unsigned short* __restrict__ Vt, const unsigned int* __restrict__ mbits,
    unsigned short* __restrict__ AO) {
  const int lane = threadIdx.x;
  const int l31 = lane & 31;
  const int h = lane >> 5;
  const int h8 = h * 8;
  // XCD-chunked swizzle: XCD x owns heads [x*3, x*3+3)
  const int f = blockIdx.x;
  const int g = (f & 7) * 192 + (f >> 3);
  const int bh = g >> 6;
  const int qb = g & 63;
  const int b = bh / HH, hd = bh - b * HH;
  const int q0 = qb * 32;
  const unsigned short* Qh = Q + (size_t)bh * TT * DD;
  const unsigned short* Kh = Kb + (size_t)bh * TT * DD;
  const unsigned short* Vh = Vt + (size_t)bh * DD * TT;
  const unsigned int* mbp = mbits + b * 64;

  bf16x8 qf[4];
#pragma unroll
  for (int dg = 0; dg < 4; ++dg)
    qf[dg] = *reinterpret_cast<const bf16x8*>(&Qh[(size_t)(q0 + l31) * DD + dg * 16 + h8]);

  f32x16 o0 = {}, o1 = {};
  float mrow = -1e30f, lrow = 0.f;

  const int nt = qb / 2 + 1;
  bf16x8 kfA[2][4], kfB[2][4];
  uint2 mbA, mbB;
  loadk(kfA, Kh, 0, l31, h8);
  mbA = *reinterpret_cast<const uint2*>(&mbp[0]);

  int t = 0;
  while (true) {
    if (t + 1 < nt) {
      loadk(kfB, Kh, (t + 1) * 64, l31, h8);
      mbB = *reinterpret_cast<const uint2*>(&mbp[(t + 1) * 2]);
    }
    attn_tile(t * 64, kfA, mbA, qf, Vh, q0, l31, h, h8, o0, o1, mrow, lrow);
    ++t; if (t >= nt) break;
    if (t + 1 < nt) {
      loadk(kfA, Kh, (t + 1) * 64, l31, h8);
      mbA = *reinterpret_cast<const uint2*>(&mbp[(t + 1) * 2]);
    }
    attn_tile(t * 64, kfB, mbB, qf, Vh, q0, l31, h, h8, o0, o1, mrow, lrow);
    ++t; if (t >= nt) break;
  }

  const float rl = 1.0f / lrow;
#pragma unroll
  for (int r = 0; r < 16; ++r) {
    const int crow = (r & 3) + 8 * (r >> 2) + 4 * h;
    const float rb = __shfl(rl, crow);
    const size_t base = (size_t)(b * TT + q0 + crow) * CC + hd * DD;
    AO[base + l31] = f2bf(o0[r] * rb);
    AO[base + 32 + l31] = f2bf(o1[r] * rb);
  }
}

extern "C" void kernel_launch(void* const* d_in, const int* in_sizes, int n_in,
                              void* d_out, int out_size, void* d_ws, size_t ws_size,
                              hipStream_t stream) {
  const float* x   = (const float*)d_in[0];
  const int* mask  = (const int*)d_in[1];
  const float* Wa  = (const float*)d_in[2];
  const float* ba  = (const float*)d_in[3];
  const float* Wp  = (const float*)d_in[4];
  const float* bp  = (const float*)d_in[5];
  float* out = (float*)d_out;

  char* ws = (char*)d_ws;
  unsigned short* Xb  = (unsigned short*)(ws);                 // [4096][768]
  unsigned short* WaT = (unsigned short*)(ws + 6291456);       // [2304][768]
  unsigned short* WpT = (unsigned short*)(ws + 9830400);       // [768][768]
  unsigned short* Qb  = (unsigned short*)(ws + 11010048);      // [24][2048][64]
  unsigned short* Kb  = (unsigned short*)(ws + 17301504);      // [24][2048][64]
  unsigned short* Vt  = (unsigned short*)(ws + 23592960);      // [24][64][2048]
  unsigned short* AO  = (unsigned short*)(ws + 29884416);      // [4096][768]
  unsigned int*   Mb  = (unsigned int*)(ws + 36175872);        // [2][64] bitmask

  k_cvt<<<dim3((MM * CC) / 4 / 256), dim3(256), 0, stream>>>(x, Xb);
  k_mbits<<<dim3(1), dim3(128), 0, stream>>>(mask, Mb);
  k_tr<<<dim3(N1 / 32, CC / 32), dim3(32, 8), 0, stream>>>(Wa, WaT, CC, N1);
  k_tr<<<dim3(CC / 32, CC / 32), dim3(32, 8), 0, stream>>>(Wp, WpT, CC, CC);

  k_gemm<1><<<dim3(MM / 128, N1 / 128), dim3(256), 0, stream>>>(
      Xb, WaT, ba, nullptr, N1, CC, Qb, Kb, Vt);

  k_attn<<<dim3(64 * BB * HH), dim3(64), 0, stream>>>(Qb, Kb, Vt, Mb, AO);

  k_gemm<0><<<dim3(MM / 128, CC / 128), dim3(256), 0, stream>>>(
      AO, WpT, bp, out, CC, CC, nullptr, nullptr, nullptr);
}